// Round 19
// baseline (112.554 us; speedup 1.0000x reference)
//
#include <hip/hip_runtime.h>
#include <hip/hip_bf16.h>
#include <math.h>

#define B_DIM 4
#define S_DIM 1024
#define D_DIM 1024
#define H_DIM 16
#define HD_DIM 64
#define M_TOT 4096

typedef short short8 __attribute__((ext_vector_type(8)));
typedef float f32x4 __attribute__((ext_vector_type(4)));

__device__ inline float bf2f(short u)
{
    return __uint_as_float(((unsigned)(unsigned short)u) << 16);
}

__device__ inline void gload_lds16(const void* gsrc, void* lds)
{
    __builtin_amdgcn_global_load_lds(
        (const __attribute__((address_space(1))) unsigned int*)gsrc,
        (__attribute__((address_space(3))) unsigned int*)lds, 16, 0, 0);
}

// ---------------------------------------------------------------------------
// Fused preamble: z<4 -> transpose 1024x1024 fp32 W -> bf16 Wt (N,K layout);
// z==4 -> RoPE cos/sin table (tab[pos*32+i]=cos, tab[32768+...]=sin).
// ---------------------------------------------------------------------------
__global__ __launch_bounds__(256) void preamble_kernel(
    const float* __restrict__ W0, const float* __restrict__ W1,
    const float* __restrict__ W2, const float* __restrict__ W3,
    __hip_bfloat16* __restrict__ T0, __hip_bfloat16* __restrict__ T1,
    __hip_bfloat16* __restrict__ T2, __hip_bfloat16* __restrict__ T3,
    float* __restrict__ tab)
{
    const int tid = threadIdx.x;
    if (blockIdx.z == 4) {
        const int fb = blockIdx.y * 32 + blockIdx.x;   // 0..1023
        if (fb >= 128) return;
        const int t = fb * 256 + tid;                  // 0..32767
        const int pos = t >> 5, i = t & 31;
        float inv = powf(10000.0f, -(float)(2 * i) / 64.0f);
        float ang = (float)pos * inv;
        float s, c;
        sincosf(ang, &s, &c);
        tab[t] = c;
        tab[32768 + t] = s;
        return;
    }

    const float* W = (blockIdx.z == 0) ? W0 : (blockIdx.z == 1) ? W1
                    : (blockIdx.z == 2) ? W2 : W3;
    __hip_bfloat16* T = (blockIdx.z == 0) ? T0 : (blockIdx.z == 1) ? T1
                       : (blockIdx.z == 2) ? T2 : T3;

    __shared__ float tile[32][33];
    const int r = tid >> 3;
    const int c4 = (tid & 7) * 4;

    float4 v = *(const float4*)&W[(long)(blockIdx.y * 32 + r) * D_DIM + blockIdx.x * 32 + c4];
    tile[r][c4 + 0] = v.x;
    tile[r][c4 + 1] = v.y;
    tile[r][c4 + 2] = v.z;
    tile[r][c4 + 3] = v.w;
    __syncthreads();

    __hip_bfloat16 o[4];
    o[0] = __float2bfloat16(tile[c4 + 0][r]);
    o[1] = __float2bfloat16(tile[c4 + 1][r]);
    o[2] = __float2bfloat16(tile[c4 + 2][r]);
    o[3] = __float2bfloat16(tile[c4 + 3][r]);
    *(uint2*)&T[(long)(blockIdx.x * 32 + r) * D_DIM + blockIdx.y * 32 + c4] = *(uint2*)o;
}

// ---------------------------------------------------------------------------
// Batched QKV GEMM, 2-DEEP pipelined (triple-buffered B, write-late A):
//   Bl[3]: B(t+2) issued at top of iter t -> ~2 iterations of latency cover.
//   A: regs loaded 1 iter ahead; cvt+ds_write AFTER the MFMAs (sched_barrier
//   pins it), so the implicit A-reg wait retires B(t+1) for free (in-order
//   vmcnt) and the pre-barrier wait is ONLY lgkmcnt(0) in steady state.
// Hazards: Bl[(t+2)%3] overwrite guarded by barrier(end of t-1); Al ping-pong
// guarded likewise; edge iters t=30/31 handled (no staging, implicit retire).
// XCD-panel-grouped swizzle; plain epilogue; z==2 -> bf16 V^T.
// ---------------------------------------------------------------------------
__global__ __launch_bounds__(256, 3) void gemm_qkv_kernel(
    const float* __restrict__ Xq, const float* __restrict__ Xk,
    const float* __restrict__ Xv,
    const __hip_bfloat16* __restrict__ WtQ, const __hip_bfloat16* __restrict__ WtK,
    const __hip_bfloat16* __restrict__ WtV,
    const float* __restrict__ bq, const float* __restrict__ bk,
    const float* __restrict__ bv,
    __hip_bfloat16* __restrict__ Qo, __hip_bfloat16* __restrict__ Ko,
    __hip_bfloat16* __restrict__ Vto)
{
    __shared__ __align__(16) __hip_bfloat16 Al[2][128][40];  // 20 KB
    __shared__ __align__(16) __hip_bfloat16 Bl[3][128][32];  // 24 KB

    // XCD-grouped work assignment (bijective on [0,768))
    const int F = blockIdx.x + 8 * blockIdx.y + 256 * blockIdx.z;
    const int xcd = F & 7;
    const int sb = F >> 3;                // 0..95
    const int z = sb >> 5;                // 0..2
    const int n0 = (sb & 7) * 128;
    const int m0 = ((xcd << 2) | ((sb >> 3) & 3)) * 128;

    const float* X = (z == 0) ? Xq : (z == 1) ? Xk : Xv;
    const __hip_bfloat16* Wt = (z == 0) ? WtQ : (z == 1) ? WtK : WtV;
    const float* bias = (z == 0) ? bq : (z == 1) ? bk : bv;

    const int tid = threadIdx.x;
    const int l = tid & 63;
    const int w = tid >> 6;

    // B staging (global_load_lds)
    const int srow = w * 16 + (l >> 2);
    const int skc = (l & 3) * 8;
    const __hip_bfloat16* Bbase = Wt + (long)(n0 + srow) * D_DIM + skc;
    char* ldsBw = (char*)&Bl[0][0][0] + w * 1024;   // + buf*8192

    // A staging: row tid>>1, 16-float chunk (tid&1)*16
    const int arow = tid >> 1;
    const int ak = (tid & 1) * 16;
    const float* Af = X + (long)(m0 + arow) * D_DIM + ak;

    const int lrow = l & 15;
    const int kg = l >> 4;
    const int wr = (w >> 1) * 64;
    const int wc = (w & 1) * 64;

    f32x4 acc[4][4];
#pragma unroll
    for (int i = 0; i < 4; ++i)
#pragma unroll
        for (int j = 0; j < 4; ++j) acc[i][j] = (f32x4){0.f, 0.f, 0.f, 0.f};

    float4 f0, f1, f2, f3;   // A regs, even-consumed set
    float4 g0, g1, g2, g3;   // A regs, odd-consumed set

    // ---- prologue ----
    {
        // A(0) -> Al[0]
        f0 = *(const float4*)(Af);
        f1 = *(const float4*)(Af + 4);
        f2 = *(const float4*)(Af + 8);
        f3 = *(const float4*)(Af + 12);
        float fa[16] = {f0.x, f0.y, f0.z, f0.w, f1.x, f1.y, f1.z, f1.w,
                        f2.x, f2.y, f2.z, f2.w, f3.x, f3.y, f3.z, f3.w};
        __attribute__((aligned(16))) __hip_bfloat16 ab[16];
#pragma unroll
        for (int i = 0; i < 16; ++i) ab[i] = __float2bfloat16(fa[i]);
        *(short8*)&Al[0][arow][ak]     = ((const short8*)ab)[0];
        *(short8*)&Al[0][arow][ak + 8] = ((const short8*)ab)[1];
        // B(0) -> Bl[0], B(1) -> Bl[1]
        gload_lds16(Bbase, ldsBw);
        gload_lds16(Bbase + 64 * D_DIM, ldsBw + 4096);
        gload_lds16(Bbase + 32, ldsBw + 8192);
        gload_lds16(Bbase + 64 * D_DIM + 32, ldsBw + 8192 + 4096);
        asm volatile("" ::: "memory");       // pin B issue before A loads
        // A(1) regs
        f0 = *(const float4*)(Af + 32);
        f1 = *(const float4*)(Af + 36);
        f2 = *(const float4*)(Af + 40);
        f3 = *(const float4*)(Af + 44);
        asm volatile("s_waitcnt vmcnt(6)" ::: "memory");   // B(0) pair retired
        asm volatile("s_waitcnt lgkmcnt(0)" ::: "memory"); // Al[0] visible
        __builtin_amdgcn_s_barrier();
    }

    int bc = 0;   // Bl buffer holding tile t (t = 2*tt in even half)
#pragma unroll 1
    for (int tt = 0; tt < 16; ++tt) {
        // ================= even half: t = 2*tt (cvt f -> Al[1]) =============
        {
            const int t = 2 * tt;
            int bn = bc + 2; if (bn >= 3) bn -= 3;
            if (tt < 15) {
                const int k2 = (t + 2) * 32;
                char* dst = ldsBw + bn * 8192;
                gload_lds16(Bbase + k2, dst);
                gload_lds16(Bbase + 64 * D_DIM + k2, dst + 4096);
                asm volatile("" ::: "memory");
                g0 = *(const float4*)(Af + k2);
                g1 = *(const float4*)(Af + k2 + 4);
                g2 = *(const float4*)(Af + k2 + 8);
                g3 = *(const float4*)(Af + k2 + 12);
            }
            const __hip_bfloat16 (*Bc)[32] =
                (const __hip_bfloat16(*)[32])((char*)&Bl[0][0][0] + bc * 8192);
            short8 af[4], bf[4];
#pragma unroll
            for (int i = 0; i < 4; ++i)
                af[i] = *(const short8*)&Al[0][wr + i * 16 + lrow][kg * 8];
#pragma unroll
            for (int j = 0; j < 4; ++j)
                bf[j] = *(const short8*)&Bc[wc + j * 16 + lrow][kg * 8];
#pragma unroll
            for (int i = 0; i < 4; ++i)
#pragma unroll
                for (int j = 0; j < 4; ++j)
                    acc[i][j] = __builtin_amdgcn_mfma_f32_16x16x32_bf16(
                        af[i], bf[j], acc[i][j], 0, 0, 0);
            __builtin_amdgcn_sched_barrier(0);
            // cvt A(t+1) (f, loaded last iter) -> Al[1]; implicit vmcnt here
            // retires B(t+1) (issued before those A loads; in-order retire).
            {
                float fa[16] = {f0.x, f0.y, f0.z, f0.w, f1.x, f1.y, f1.z, f1.w,
                                f2.x, f2.y, f2.z, f2.w, f3.x, f3.y, f3.z, f3.w};
                __attribute__((aligned(16))) __hip_bfloat16 ab[16];
#pragma unroll
                for (int i = 0; i < 16; ++i) ab[i] = __float2bfloat16(fa[i]);
                *(short8*)&Al[1][arow][ak]     = ((const short8*)ab)[0];
                *(short8*)&Al[1][arow][ak + 8] = ((const short8*)ab)[1];
            }
            asm volatile("s_waitcnt lgkmcnt(0)" ::: "memory");
            __builtin_amdgcn_s_barrier();
            bc = bc + 1; if (bc >= 3) bc -= 3;
        }
        // ================= odd half: t = 2*tt+1 (cvt g -> Al[0]) ============
        {
            const int t = 2 * tt + 1;
            int bn = bc + 2; if (bn >= 3) bn -= 3;
            if (tt < 15) {
                const int k2 = (t + 2) * 32;
                char* dst = ldsBw + bn * 8192;
                gload_lds16(Bbase + k2, dst);
                gload_lds16(Bbase + 64 * D_DIM + k2, dst + 4096);
                asm volatile("" ::: "memory");
                f0 = *(const float4*)(Af + k2);
                f1 = *(const float4*)(Af + k2 + 4);
                f2 = *(const float4*)(Af + k2 + 8);
                f3 = *(const float4*)(Af + k2 + 12);
            }
            const __hip_bfloat16 (*Bc)[32] =
                (const __hip_bfloat16(*)[32])((char*)&Bl[0][0][0] + bc * 8192);
            short8 af[4], bf[4];
#pragma unroll
            for (int i = 0; i < 4; ++i)
                af[i] = *(const short8*)&Al[1][wr + i * 16 + lrow][kg * 8];
#pragma unroll
            for (int j = 0; j < 4; ++j)
                bf[j] = *(const short8*)&Bc[wc + j * 16 + lrow][kg * 8];
#pragma unroll
            for (int i = 0; i < 4; ++i)
#pragma unroll
                for (int j = 0; j < 4; ++j)
                    acc[i][j] = __builtin_amdgcn_mfma_f32_16x16x32_bf16(
                        af[i], bf[j], acc[i][j], 0, 0, 0);
            if (tt < 15) {
                __builtin_amdgcn_sched_barrier(0);
                float fa[16] = {g0.x, g0.y, g0.z, g0.w, g1.x, g1.y, g1.z, g1.w,
                                g2.x, g2.y, g2.z, g2.w, g3.x, g3.y, g3.z, g3.w};
                __attribute__((aligned(16))) __hip_bfloat16 ab[16];
#pragma unroll
                for (int i = 0; i < 16; ++i) ab[i] = __float2bfloat16(fa[i]);
                *(short8*)&Al[0][arow][ak]     = ((const short8*)ab)[0];
                *(short8*)&Al[0][arow][ak + 8] = ((const short8*)ab)[1];
                asm volatile("s_waitcnt lgkmcnt(0)" ::: "memory");
                __builtin_amdgcn_s_barrier();
            }
            bc = bc + 1; if (bc >= 3) bc -= 3;
        }
    }

    // epilogue (C/D: col = lane&15, row = (lane>>4)*4 + reg)
#pragma unroll
    for (int i = 0; i < 4; ++i) {
#pragma unroll
        for (int j = 0; j < 4; ++j) {
            const int col = n0 + wc + j * 16 + lrow;
            const float bvs = bias[col];
            const int rbase = m0 + wr + i * 16 + kg * 4;
            if (z < 2) {
                __hip_bfloat16* Out = (z == 0) ? Qo : Ko;
#pragma unroll
                for (int r = 0; r < 4; ++r)
                    Out[(long)(rbase + r) * D_DIM + col] =
                        __float2bfloat16(acc[i][j][r] + bvs);
            } else {
                const int hh = col >> 6, dd = col & 63;
                const int bb = rbase >> 10, s0 = rbase & 1023;
                __hip_bfloat16 o[4];
#pragma unroll
                for (int r = 0; r < 4; ++r)
                    o[r] = __float2bfloat16(acc[i][j][r] + bvs);
                *(uint2*)&Vto[((long)((bb * H_DIM + hh) * HD_DIM + dd)) * S_DIM + s0] =
                    *(uint2*)o;
            }
        }
    }
}

// ---------------------------------------------------------------------------
// Final projection: Out(M,N fp32) = X(M,K bf16) @ Wt(N,K bf16)^T + bias
// 128x64 tile -> 512 blocks (2/CU) + XCD swizzle.
// ---------------------------------------------------------------------------
__global__ __launch_bounds__(256, 2) void gemm_wo_kernel(
    const __hip_bfloat16* __restrict__ X, const __hip_bfloat16* __restrict__ Wt,
    const float* __restrict__ bias, float* __restrict__ Out)
{
    __shared__ __align__(16) __hip_bfloat16 Al[128][32];  // 8 KB
    __shared__ __align__(16) __hip_bfloat16 Bl[64][32];   // 4 KB

    const int F = blockIdx.x;
    const int xcd = F & 7;
    const int s = F >> 3;                 // 0..63
    const int n0 = (s & 15) * 64;
    const int m0 = ((xcd << 2) | (s >> 4)) * 128;

    const int tid = threadIdx.x;
    const int l = tid & 63;
    const int w = tid >> 6;

    const int srow = w * 16 + (l >> 2);
    const int skc = (l & 3) * 8;
    const __hip_bfloat16* Abase = X + (long)(m0 + srow) * D_DIM + skc;
    const __hip_bfloat16* Bbase = Wt + (long)(n0 + srow) * D_DIM + skc;
    char* ldsA0 = (char*)&Al[0][0] + w * 1024;
    char* ldsB0 = (char*)&Bl[0][0] + w * 1024;

    const int lrow = l & 15;
    const int kg = l >> 4;
    const int wr = (w >> 1) * 64;   // wave row: 0 / 64
    const int wc = (w & 1) * 32;    // wave col: 0 / 32

    f32x4 acc[4][2];
#pragma unroll
    for (int i = 0; i < 4; ++i)
#pragma unroll
        for (int j = 0; j < 2; ++j) acc[i][j] = (f32x4){0.f, 0.f, 0.f, 0.f};

    for (int k0 = 0; k0 < D_DIM; k0 += 32) {
        __syncthreads();
        gload_lds16(Abase + k0, ldsA0);
        gload_lds16(Abase + 64 * D_DIM + k0, ldsA0 + 4096);
        gload_lds16(Bbase + k0, ldsB0);
        __syncthreads();

        short8 af[4], bf[2];
#pragma unroll
        for (int i = 0; i < 4; ++i)
            af[i] = *(const short8*)&Al[wr + i * 16 + lrow][kg * 8];
#pragma unroll
        for (int j = 0; j < 2; ++j)
            bf[j] = *(const short8*)&Bl[wc + j * 16 + lrow][kg * 8];
#pragma unroll
        for (int i = 0; i < 4; ++i)
#pragma unroll
            for (int j = 0; j < 2; ++j)
                acc[i][j] = __builtin_amdgcn_mfma_f32_16x16x32_bf16(
                    af[i], bf[j], acc[i][j], 0, 0, 0);
    }

#pragma unroll
    for (int i = 0; i < 4; ++i) {
#pragma unroll
        for (int j = 0; j < 2; ++j) {
            const int col = n0 + wc + j * 16 + lrow;
            const float bv = bias[col];
            const int rbase = m0 + wr + i * 16 + kg * 4;
#pragma unroll
            for (int r = 0; r < 4; ++r)
                Out[(long)(rbase + r) * D_DIM + col] = acc[i][j][r] + bv;
        }
    }
}

// ---------------------------------------------------------------------------
// RoPE: bf16 in -> bf16 out, table-driven. Q additionally scaled by 1/8.
// ---------------------------------------------------------------------------
__global__ __launch_bounds__(256) void rope_bf16_kernel(
    const __hip_bfloat16* __restrict__ Qi, const __hip_bfloat16* __restrict__ Ki,
    __hip_bfloat16* __restrict__ Qo, __hip_bfloat16* __restrict__ Ko,
    const float* __restrict__ tab)
{
    const long t = (long)blockIdx.x * 256 + threadIdx.x;  // 0..524287
    const int row = (int)(t >> 7);
    const int slot = (int)(t & 127);
    const int hh = slot >> 3;
    const int p0 = (slot & 7) * 4;
    const int pos = row & (S_DIM - 1);
    const bool isQ = (blockIdx.y == 0);
    const float scale = isQ ? 0.125f : 1.0f;

    const __hip_bfloat16* src = (isQ ? Qi : Ki) + (long)row * D_DIM + hh * HD_DIM;
    __hip_bfloat16* dst = (isQ ? Qo : Ko) + (long)row * D_DIM + hh * HD_DIM;

    short8 xv = *(const short8*)&src[2 * p0];
    float4 cv = *(const float4*)&tab[pos * 32 + p0];
    float4 sv = *(const float4*)&tab[32768 + pos * 32 + p0];
    float cc[4] = {cv.x, cv.y, cv.z, cv.w};
    float ss[4] = {sv.x, sv.y, sv.z, sv.w};

    __hip_bfloat16 o1[4], o2[4];
#pragma unroll
    for (int j = 0; j < 4; ++j) {
        float x1 = bf2f(xv[2 * j]);
        float x2 = bf2f(xv[2 * j + 1]);
        o1[j] = __float2bfloat16((x1 * cc[j] - x2 * ss[j]) * scale);
        o2[j] = __float2bfloat16((x1 * ss[j] + x2 * cc[j]) * scale);
    }
    *(uint2*)&dst[p0]      = *(uint2*)o1;
    *(uint2*)&dst[p0 + 32] = *(uint2*)o2;
}

// ---------------------------------------------------------------------------
// MFMA flash attention, swapped-QK^T softmax, prefetched staging, balanced qt.
// ---------------------------------------------------------------------------
#define KPAD 72

__global__ __launch_bounds__(256, 2) void attn_mfma_kernel(
    const __hip_bfloat16* __restrict__ Q,
    const __hip_bfloat16* __restrict__ K,
    const __hip_bfloat16* __restrict__ Vt,
    __hip_bfloat16* __restrict__ CTX)
{
    __shared__ __align__(16) __hip_bfloat16 Kl[64][KPAD];
    __shared__ __align__(16) __hip_bfloat16 Vl[64][KPAD];
    __shared__ __align__(16) __hip_bfloat16 Pl[4][32][KPAD];
    __shared__ __align__(16) float aS[4][2][16];

    const int tid = threadIdx.x;
    const int l = tid & 63;
    const int w = tid >> 6;

    const int bid = blockIdx.x + 8 * blockIdx.y + 128 * blockIdx.z;
    const int half = bid >> 8;
    const int idx = bid & 255;
    int qt = idx & 7;
    if (half) qt = 7 - qt;
    const int rest = idx >> 3;
    const int h = rest & 15;
    const int b = (rest >> 4) | (half << 1);

    const int lrow = l & 15;
    const int kg = l >> 4;
    const int kg4 = kg * 4;

    const int q0w = qt * 128 + w * 32;
    const long qrow_base = (long)b * S_DIM + q0w;

    short8 qf[2][2];
#pragma unroll
    for (int m = 0; m < 2; ++m)
#pragma unroll
        for (int ks = 0; ks < 2; ++ks)
            qf[m][ks] = *(const short8*)&Q[(qrow_base + m * 16 + lrow) * D_DIM +
                                           h * HD_DIM + ks * 32 + kg * 8];

    f32x4 ctx[2][4];
#pragma unroll
    for (int m = 0; m < 2; ++m)
#pragma unroll
        for (int d = 0; d < 4; ++d) ctx[m][d] = (f32x4){0.f, 0.f, 0.f, 0.f};
    float mrun[2] = {-1e30f, -1e30f};
    float lrun[2] = {0.f, 0.f};

    const int sr = tid >> 2;
    const int sc2 = (tid & 3) * 16;
    const __hip_bfloat16* Kg = K + ((long)b * S_DIM + sr) * D_DIM + h * HD_DIM + sc2;
    const __hip_bfloat16* Vg = Vt + ((long)((b * H_DIM + h) * HD_DIM) + sr) * S_DIM + sc2;

    const int ktmax = 2 * qt + 1;

    short8 kp0 = *(const short8*)Kg;
    short8 kp1 = *(const short8*)(Kg + 8);
    short8 vp0 = *(const short8*)Vg;
    short8 vp1 = *(const short8*)(Vg + 8);

    for (int kt = 0; kt <= ktmax; ++kt) {
        __syncthreads();
        *(short8*)&Kl[sr][sc2]     = kp0;
        *(short8*)&Kl[sr][sc2 + 8] = kp1;
        *(short8*)&Vl[sr][sc2]     = vp0;
        *(short8*)&Vl[sr][sc2 + 8] = vp1;
        if (kt < ktmax) {
            const __hip_bfloat16* kp = Kg + (long)(kt + 1) * 64 * D_DIM;
            const __hip_bfloat16* vp = Vg + (kt + 1) * 64;
            kp0 = *(const short8*)kp;
            kp1 = *(const short8*)(kp + 8);
            vp0 = *(const short8*)vp;
            vp1 = *(const short8*)(vp + 8);
        }
        __syncthreads();

        if (kt * 64 > q0w + 31) continue;

        f32x4 sac[2][4];
#pragma unroll
        for (int m = 0; m < 2; ++m)
#pragma unroll
            for (int nt = 0; nt < 4; ++nt) sac[m][nt] = (f32x4){0.f, 0.f, 0.f, 0.f};

        short8 kf[4][2];
#pragma unroll
        for (int nt = 0; nt < 4; ++nt)
#pragma unroll
            for (int ks = 0; ks < 2; ++ks)
                kf[nt][ks] = *(const short8*)&Kl[nt * 16 + lrow][ks * 32 + kg * 8];
#pragma unroll
        for (int m = 0; m < 2; ++m)
#pragma unroll
            for (int nt = 0; nt < 4; ++nt)
#pragma unroll
                for (int ks = 0; ks < 2; ++ks)
                    sac[m][nt] = __builtin_amdgcn_mfma_f32_16x16x32_bf16(
                        kf[nt][ks], qf[m][ks], sac[m][nt], 0, 0, 0);

        const bool partial = (kt * 64 + 63 > q0w);
        const int kbase = kt * 64;
#pragma unroll
        for (int m = 0; m < 2; ++m) {
            const int qg = q0w + m * 16 + lrow;
            float s[16];
#pragma unroll
            for (int nt = 0; nt < 4; ++nt)
#pragma unroll
                for (int r = 0; r < 4; ++r) {
                    float v = sac[m][nt][r];
                    if (partial && (kbase + nt * 16 + kg4 + r > qg)) v = -1e30f;
                    s[nt * 4 + r] = v;
                }
            float t8[8];
#pragma unroll
            for (int i = 0; i < 8; ++i) t8[i] = fmaxf(s[i], s[i + 8]);
#pragma unroll
            for (int i = 0; i < 4; ++i) t8[i] = fmaxf(t8[i], t8[i + 4]);
            float mx = fmaxf(fmaxf(t8[0], t8[1]), fmaxf(t8[2], t8[3]));
            mx = fmaxf(mx, __shfl_xor(mx, 16));
            mx = fmaxf(mx, __shfl_xor(mx, 32));
            const float mnew = fmaxf(mrun[m], mx);
            const float alpha = __expf(mrun[m] - mnew);
            mrun[m] = mnew;

            float p0s = 0.f, p1s = 0.f, p2s = 0.f, p3s = 0.f;
            __attribute__((aligned(8))) __hip_bfloat16 pb[16];
#pragma unroll
            for (int i = 0; i < 4; ++i) {
                float p = __expf(s[i] - mnew);      p0s += p; pb[i] = __float2bfloat16(p);
            }
#pragma unroll
            for (int i = 4; i < 8; ++i) {
                float p = __expf(s[i] - mnew);      p1s += p; pb[i] = __float2bfloat16(p);
            }
#pragma unroll
            for (int i = 8; i < 12; ++i) {
                float p = __expf(s[i] - mnew);      p2s += p; pb[i] = __float2bfloat16(p);
            }
#pragma unroll
            for (int i = 12; i < 16; ++i) {
                float p = __expf(s[i] - mnew);      p3s += p; pb[i] = __float2bfloat16(p);
            }
            float sum = (p0s + p1s) + (p2s + p3s);
            sum += __shfl_xor(sum, 16);
            sum += __shfl_xor(sum, 32);
            lrun[m] = lrun[m] * alpha + sum;

            if (kg == 0) aS[w][m][lrow] = alpha;
#pragma unroll
            for (int nt = 0; nt < 4; ++nt)
                *(uint2*)&Pl[w][m * 16 + lrow][nt * 16 + kg4] = *(uint2*)&pb[nt * 4];
        }

#pragma unroll
        for (int m = 0; m < 2; ++m) {
            f32x4 al4 = *(const f32x4*)&aS[w][m][kg4];
#pragma unroll
            for (int dt = 0; dt < 4; ++dt)
#pragma unroll
                for (int r = 0; r < 4; ++r) ctx[m][dt][r] *= al4[r];
        }

        short8 vf[4][2];
#pragma unroll
        for (int dt = 0; dt < 4; ++dt)
#pragma unroll
            for (int ks = 0; ks < 2; ++ks)
                vf[dt][ks] = *(const short8*)&Vl[dt * 16 + lrow][ks * 32 + kg * 8];
#pragma unroll
        for (int m = 0; m < 2; ++m) {
            short8 pf[2];
#pragma unroll
            for (int ks = 0; ks < 2; ++ks)
                pf[ks] = *(const short8*)&Pl[w][m * 16 + lrow][ks * 32 + kg * 8];
#pragma unroll
            for (int dt = 0; dt < 4; ++dt)
#pragma unroll
                for (int ks = 0; ks < 2; ++ks)
                    ctx[m][dt] = __builtin_amdgcn_mfma_f32_16x16x32_bf16(
                        pf[ks], vf[dt][ks], ctx[m][dt], 0, 0, 0);
        }
    }

    if (kg == 0) {
        aS[w][0][lrow] = lrun[0];
        aS[w][1][lrow] = lrun[1];
    }
#pragma unroll
    for (int m = 0; m < 2; ++m) {
        f32x4 lv = *(const f32x4*)&aS[w][m][kg4];
#pragma unroll
        for (int r = 0; r < 4; ++r) {
            const float inv_l = 1.0f / lv[r];
            const long rowoff = (qrow_base + m * 16 + kg4 + r) * D_DIM + h * HD_DIM;
#pragma unroll
            for (int dt = 0; dt < 4; ++dt)
                CTX[rowoff + dt * 16 + lrow] = __float2bfloat16(ctx[m][dt][r] * inv_l);
        }
    }
}

// ---------------------------------------------------------------------------
extern "C" void kernel_launch(void* const* d_in, const int* in_sizes, int n_in,
                              void* d_out, int out_size, void* d_ws, size_t ws_size,
                              hipStream_t stream)
{
    const float* query = (const float*)d_in[0];
    const float* key   = (const float*)d_in[1];
    const float* value = (const float*)d_in[2];
    const float* Wq = (const float*)d_in[4];
    const float* bq = (const float*)d_in[5];
    const float* Wk = (const float*)d_in[6];
    const float* bk = (const float*)d_in[7];
    const float* Wv = (const float*)d_in[8];
    const float* bv = (const float*)d_in[9];
    const float* Wo = (const float*)d_in[10];
    const float* bo = (const float*)d_in[11];

    char* wsb = (char*)d_ws;
    __hip_bfloat16* Qw    = (__hip_bfloat16*)(wsb);                 // 8 MB (pre-rope)
    __hip_bfloat16* Kw    = (__hip_bfloat16*)(wsb + (8L  << 20));   // 8 MB
    __hip_bfloat16* Vtb   = (__hip_bfloat16*)(wsb + (16L << 20));   // 8 MB
    __hip_bfloat16* Qr    = (__hip_bfloat16*)(wsb + (24L << 20));   // 8 MB (roped)
    __hip_bfloat16* Kr    = (__hip_bfloat16*)(wsb + (32L << 20));   // 8 MB (roped)
    __hip_bfloat16* CTXbf = (__hip_bfloat16*)(wsb + (40L << 20));   // 8 MB
    __hip_bfloat16* WtQ   = (__hip_bfloat16*)(wsb + (48L << 20));   // 2 MB
    __hip_bfloat16* WtK   = (__hip_bfloat16*)(wsb + (50L << 20));
    __hip_bfloat16* WtV   = (__hip_bfloat16*)(wsb + (52L << 20));
    __hip_bfloat16* WtO   = (__hip_bfloat16*)(wsb + (54L << 20));
    float*          tab   = (float*)(wsb + (56L << 20));            // 256 KB

    preamble_kernel<<<dim3(32, 32, 5), 256, 0, stream>>>(
        Wq, Wk, Wv, Wo, WtQ, WtK, WtV, WtO, tab);

    gemm_qkv_kernel<<<dim3(8, 32, 3), 256, 0, stream>>>(
        query, key, value, WtQ, WtK, WtV, bq, bk, bv, Qw, Kw, Vtb);

    rope_bf16_kernel<<<dim3(2048, 2), 256, 0, stream>>>(Qw, Kw, Qr, Kr, tab);

    attn_mfma_kernel<<<dim3(8, 16, 4), 256, 0, stream>>>(Qr, Kr, Vtb, CTXbf);

    gemm_wo_kernel<<<512, 256, 0, stream>>>(CTXbf, WtO, bo, (float*)d_out);
}

// Round 20
// 110.803 us; speedup vs baseline: 1.0158x; 1.0158x over previous
//
#include <hip/hip_runtime.h>
#include <hip/hip_bf16.h>
#include <math.h>

#define B_DIM 4
#define S_DIM 1024
#define D_DIM 1024
#define H_DIM 16
#define HD_DIM 64
#define M_TOT 4096

typedef short short8 __attribute__((ext_vector_type(8)));
typedef float f32x4 __attribute__((ext_vector_type(4)));

__device__ inline float bf2f(short u)
{
    return __uint_as_float(((unsigned)(unsigned short)u) << 16);
}

__device__ inline void gload_lds16(const void* gsrc, void* lds)
{
    __builtin_amdgcn_global_load_lds(
        (const __attribute__((address_space(1))) unsigned int*)gsrc,
        (__attribute__((address_space(3))) unsigned int*)lds, 16, 0, 0);
}

// ---------------------------------------------------------------------------
// Fused preamble: z<4 -> transpose 1024x1024 fp32 W -> bf16 Wt (N,K layout);
// z==4 -> RoPE cos/sin table (tab[pos*32+i]=cos, tab[32768+...]=sin).
// ---------------------------------------------------------------------------
__global__ __launch_bounds__(256) void preamble_kernel(
    const float* __restrict__ W0, const float* __restrict__ W1,
    const float* __restrict__ W2, const float* __restrict__ W3,
    __hip_bfloat16* __restrict__ T0, __hip_bfloat16* __restrict__ T1,
    __hip_bfloat16* __restrict__ T2, __hip_bfloat16* __restrict__ T3,
    float* __restrict__ tab)
{
    const int tid = threadIdx.x;
    if (blockIdx.z == 4) {
        const int fb = blockIdx.y * 32 + blockIdx.x;   // 0..1023
        if (fb >= 128) return;
        const int t = fb * 256 + tid;                  // 0..32767
        const int pos = t >> 5, i = t & 31;
        float inv = powf(10000.0f, -(float)(2 * i) / 64.0f);
        float ang = (float)pos * inv;
        float s, c;
        sincosf(ang, &s, &c);
        tab[t] = c;
        tab[32768 + t] = s;
        return;
    }

    const float* W = (blockIdx.z == 0) ? W0 : (blockIdx.z == 1) ? W1
                    : (blockIdx.z == 2) ? W2 : W3;
    __hip_bfloat16* T = (blockIdx.z == 0) ? T0 : (blockIdx.z == 1) ? T1
                       : (blockIdx.z == 2) ? T2 : T3;

    __shared__ float tile[32][33];
    const int r = tid >> 3;
    const int c4 = (tid & 7) * 4;

    float4 v = *(const float4*)&W[(long)(blockIdx.y * 32 + r) * D_DIM + blockIdx.x * 32 + c4];
    tile[r][c4 + 0] = v.x;
    tile[r][c4 + 1] = v.y;
    tile[r][c4 + 2] = v.z;
    tile[r][c4 + 3] = v.w;
    __syncthreads();

    __hip_bfloat16 o[4];
    o[0] = __float2bfloat16(tile[c4 + 0][r]);
    o[1] = __float2bfloat16(tile[c4 + 1][r]);
    o[2] = __float2bfloat16(tile[c4 + 2][r]);
    o[3] = __float2bfloat16(tile[c4 + 3][r]);
    *(uint2*)&T[(long)(blockIdx.x * 32 + r) * D_DIM + blockIdx.y * 32 + c4] = *(uint2*)o;
}

// ---------------------------------------------------------------------------
// Batched QKV GEMM, counted-vmcnt pipeline (r18-verified best):
// LDS double buffer: Al[2][128][40] (padded, reg-staged A), Bl[2][128][32].
// Per K-step t (p=t&1, q=p^1): issue B(t+1) gloads + cvt/ds_write A(t+1);
// load A regs for t+2; MFMA from buffers[p]; then s_waitcnt vmcnt(4)
// (A loads may remain in flight) + lgkmcnt(0) + raw barrier.
// XCD-panel-grouped swizzle; plain epilogue; z==2 -> bf16 V^T.
// ---------------------------------------------------------------------------
__global__ __launch_bounds__(256, 3) void gemm_qkv_kernel(
    const float* __restrict__ Xq, const float* __restrict__ Xk,
    const float* __restrict__ Xv,
    const __hip_bfloat16* __restrict__ WtQ, const __hip_bfloat16* __restrict__ WtK,
    const __hip_bfloat16* __restrict__ WtV,
    const float* __restrict__ bq, const float* __restrict__ bk,
    const float* __restrict__ bv,
    __hip_bfloat16* __restrict__ Qo, __hip_bfloat16* __restrict__ Ko,
    __hip_bfloat16* __restrict__ Vto)
{
    __shared__ __align__(16) __hip_bfloat16 Al[2][128][40];  // 20 KB
    __shared__ __align__(16) __hip_bfloat16 Bl[2][128][32];  // 16 KB

    // XCD-grouped work assignment (bijective on [0,768))
    const int F = blockIdx.x + 8 * blockIdx.y + 256 * blockIdx.z;
    const int xcd = F & 7;
    const int sb = F >> 3;                // 0..95
    const int z = sb >> 5;                // 0..2
    const int n0 = (sb & 7) * 128;
    const int m0 = ((xcd << 2) | ((sb >> 3) & 3)) * 128;

    const float* X = (z == 0) ? Xq : (z == 1) ? Xk : Xv;
    const __hip_bfloat16* Wt = (z == 0) ? WtQ : (z == 1) ? WtK : WtV;
    const float* bias = (z == 0) ? bq : (z == 1) ? bk : bv;

    const int tid = threadIdx.x;
    const int l = tid & 63;
    const int w = tid >> 6;

    // B staging (global_load_lds)
    const int srow = w * 16 + (l >> 2);
    const int skc = (l & 3) * 8;
    const __hip_bfloat16* Bbase = Wt + (long)(n0 + srow) * D_DIM + skc;
    char* ldsB0 = (char*)&Bl[0][0][0] + w * 1024;
    char* ldsB1 = (char*)&Bl[1][0][0] + w * 1024;

    // A staging: row tid>>1, 16-float chunk (tid&1)*16
    const int arow = tid >> 1;
    const int ak = (tid & 1) * 16;
    const float* Af = X + (long)(m0 + arow) * D_DIM + ak;

    const int lrow = l & 15;
    const int kg = l >> 4;
    const int wr = (w >> 1) * 64;
    const int wc = (w & 1) * 64;

    f32x4 acc[4][4];
#pragma unroll
    for (int i = 0; i < 4; ++i)
#pragma unroll
        for (int j = 0; j < 4; ++j) acc[i][j] = (f32x4){0.f, 0.f, 0.f, 0.f};

    float4 f0, f1, f2, f3;

    // ---- prologue: stage k-step 0 into buffer 0; prefetch A for k-step 1 ----
    {
        f0 = *(const float4*)(Af);
        f1 = *(const float4*)(Af + 4);
        f2 = *(const float4*)(Af + 8);
        f3 = *(const float4*)(Af + 12);
        float fa[16] = {f0.x, f0.y, f0.z, f0.w, f1.x, f1.y, f1.z, f1.w,
                        f2.x, f2.y, f2.z, f2.w, f3.x, f3.y, f3.z, f3.w};
        __attribute__((aligned(16))) __hip_bfloat16 ab[16];
#pragma unroll
        for (int i = 0; i < 16; ++i) ab[i] = __float2bfloat16(fa[i]);
        *(short8*)&Al[0][arow][ak]     = ((const short8*)ab)[0];
        *(short8*)&Al[0][arow][ak + 8] = ((const short8*)ab)[1];
        gload_lds16(Bbase, ldsB0);
        gload_lds16(Bbase + 64 * D_DIM, ldsB0 + 4096);
        asm volatile("" ::: "memory");       // pin gload issue before A loads
        f0 = *(const float4*)(Af + 32);
        f1 = *(const float4*)(Af + 36);
        f2 = *(const float4*)(Af + 40);
        f3 = *(const float4*)(Af + 44);
        asm volatile("s_waitcnt vmcnt(4)" ::: "memory");   // B gloads done
        asm volatile("s_waitcnt lgkmcnt(0)" ::: "memory"); // ds_writes visible
        __builtin_amdgcn_s_barrier();
    }

    for (int t = 0; t < 32; ++t) {
        const int p = t & 1;
        const int q = p ^ 1;
        char* ldsBq = (q == 0) ? ldsB0 : ldsB1;

        if (t < 31) {
            // a. issue next B tile (in flight under this iteration's MFMA)
            const int k1 = (t + 1) * 32;
            gload_lds16(Bbase + k1, ldsBq);
            gload_lds16(Bbase + 64 * D_DIM + k1, ldsBq + 4096);
            // b. cvt A regs (loaded at t-1, fully covered) -> Al[q]
            float fa[16] = {f0.x, f0.y, f0.z, f0.w, f1.x, f1.y, f1.z, f1.w,
                            f2.x, f2.y, f2.z, f2.w, f3.x, f3.y, f3.z, f3.w};
            __attribute__((aligned(16))) __hip_bfloat16 ab[16];
#pragma unroll
            for (int i = 0; i < 16; ++i) ab[i] = __float2bfloat16(fa[i]);
            *(short8*)&Al[q][arow][ak]     = ((const short8*)ab)[0];
            *(short8*)&Al[q][arow][ak + 8] = ((const short8*)ab)[1];
        }
        asm volatile("" ::: "memory");       // pin B gloads before A loads
        if (t < 30) {
            // c. prefetch A regs for k-step t+2
            const int k2 = (t + 2) * 32;
            f0 = *(const float4*)(Af + k2);
            f1 = *(const float4*)(Af + k2 + 4);
            f2 = *(const float4*)(Af + k2 + 8);
            f3 = *(const float4*)(Af + k2 + 12);
        }

        // d. compute from buffer p
        short8 af[4], bf[4];
#pragma unroll
        for (int i = 0; i < 4; ++i)
            af[i] = *(const short8*)&Al[p][wr + i * 16 + lrow][kg * 8];
#pragma unroll
        for (int j = 0; j < 4; ++j)
            bf[j] = *(const short8*)&Bl[p][wc + j * 16 + lrow][kg * 8];
#pragma unroll
        for (int i = 0; i < 4; ++i)
#pragma unroll
            for (int j = 0; j < 4; ++j)
                acc[i][j] = __builtin_amdgcn_mfma_f32_16x16x32_bf16(
                    af[i], bf[j], acc[i][j], 0, 0, 0);

        // e. counted waits + raw barrier (no full vmcnt drain in steady state)
        if (t < 31) {
            if (t < 30)
                asm volatile("s_waitcnt vmcnt(4)" ::: "memory");  // B done; A(t+2) in flight
            else
                asm volatile("s_waitcnt vmcnt(0)" ::: "memory");  // last B pair
            asm volatile("s_waitcnt lgkmcnt(0)" ::: "memory");
            __builtin_amdgcn_s_barrier();
        }
    }

    // epilogue (C/D: col = lane&15, row = (lane>>4)*4 + reg)
#pragma unroll
    for (int i = 0; i < 4; ++i) {
#pragma unroll
        for (int j = 0; j < 4; ++j) {
            const int col = n0 + wc + j * 16 + lrow;
            const float bvs = bias[col];
            const int rbase = m0 + wr + i * 16 + kg * 4;
            if (z < 2) {
                __hip_bfloat16* Out = (z == 0) ? Qo : Ko;
#pragma unroll
                for (int r = 0; r < 4; ++r)
                    Out[(long)(rbase + r) * D_DIM + col] =
                        __float2bfloat16(acc[i][j][r] + bvs);
            } else {
                const int hh = col >> 6, dd = col & 63;
                const int bb = rbase >> 10, s0 = rbase & 1023;
                __hip_bfloat16 o[4];
#pragma unroll
                for (int r = 0; r < 4; ++r)
                    o[r] = __float2bfloat16(acc[i][j][r] + bvs);
                *(uint2*)&Vto[((long)((bb * H_DIM + hh) * HD_DIM + dd)) * S_DIM + s0] =
                    *(uint2*)o;
            }
        }
    }
}

// ---------------------------------------------------------------------------
// Final projection: Out(M,N fp32) = X(M,K bf16) @ Wt(N,K bf16)^T + bias
// 128x64 tile -> 512 blocks (2/CU) + XCD swizzle.
// ---------------------------------------------------------------------------
__global__ __launch_bounds__(256, 2) void gemm_wo_kernel(
    const __hip_bfloat16* __restrict__ X, const __hip_bfloat16* __restrict__ Wt,
    const float* __restrict__ bias, float* __restrict__ Out)
{
    __shared__ __align__(16) __hip_bfloat16 Al[128][32];  // 8 KB
    __shared__ __align__(16) __hip_bfloat16 Bl[64][32];   // 4 KB

    const int F = blockIdx.x;
    const int xcd = F & 7;
    const int s = F >> 3;                 // 0..63
    const int n0 = (s & 15) * 64;
    const int m0 = ((xcd << 2) | (s >> 4)) * 128;

    const int tid = threadIdx.x;
    const int l = tid & 63;
    const int w = tid >> 6;

    const int srow = w * 16 + (l >> 2);
    const int skc = (l & 3) * 8;
    const __hip_bfloat16* Abase = X + (long)(m0 + srow) * D_DIM + skc;
    const __hip_bfloat16* Bbase = Wt + (long)(n0 + srow) * D_DIM + skc;
    char* ldsA0 = (char*)&Al[0][0] + w * 1024;
    char* ldsB0 = (char*)&Bl[0][0] + w * 1024;

    const int lrow = l & 15;
    const int kg = l >> 4;
    const int wr = (w >> 1) * 64;   // wave row: 0 / 64
    const int wc = (w & 1) * 32;    // wave col: 0 / 32

    f32x4 acc[4][2];
#pragma unroll
    for (int i = 0; i < 4; ++i)
#pragma unroll
        for (int j = 0; j < 2; ++j) acc[i][j] = (f32x4){0.f, 0.f, 0.f, 0.f};

    for (int k0 = 0; k0 < D_DIM; k0 += 32) {
        __syncthreads();
        gload_lds16(Abase + k0, ldsA0);
        gload_lds16(Abase + 64 * D_DIM + k0, ldsA0 + 4096);
        gload_lds16(Bbase + k0, ldsB0);
        __syncthreads();

        short8 af[4], bf[2];
#pragma unroll
        for (int i = 0; i < 4; ++i)
            af[i] = *(const short8*)&Al[wr + i * 16 + lrow][kg * 8];
#pragma unroll
        for (int j = 0; j < 2; ++j)
            bf[j] = *(const short8*)&Bl[wc + j * 16 + lrow][kg * 8];
#pragma unroll
        for (int i = 0; i < 4; ++i)
#pragma unroll
            for (int j = 0; j < 2; ++j)
                acc[i][j] = __builtin_amdgcn_mfma_f32_16x16x32_bf16(
                    af[i], bf[j], acc[i][j], 0, 0, 0);
    }

#pragma unroll
    for (int i = 0; i < 4; ++i) {
#pragma unroll
        for (int j = 0; j < 2; ++j) {
            const int col = n0 + wc + j * 16 + lrow;
            const float bv = bias[col];
            const int rbase = m0 + wr + i * 16 + kg * 4;
#pragma unroll
            for (int r = 0; r < 4; ++r)
                Out[(long)(rbase + r) * D_DIM + col] = acc[i][j][r] + bv;
        }
    }
}

// ---------------------------------------------------------------------------
// RoPE: bf16 in -> bf16 out, table-driven. Q additionally scaled by 1/8.
// ---------------------------------------------------------------------------
__global__ __launch_bounds__(256) void rope_bf16_kernel(
    const __hip_bfloat16* __restrict__ Qi, const __hip_bfloat16* __restrict__ Ki,
    __hip_bfloat16* __restrict__ Qo, __hip_bfloat16* __restrict__ Ko,
    const float* __restrict__ tab)
{
    const long t = (long)blockIdx.x * 256 + threadIdx.x;  // 0..524287
    const int row = (int)(t >> 7);
    const int slot = (int)(t & 127);
    const int hh = slot >> 3;
    const int p0 = (slot & 7) * 4;
    const int pos = row & (S_DIM - 1);
    const bool isQ = (blockIdx.y == 0);
    const float scale = isQ ? 0.125f : 1.0f;

    const __hip_bfloat16* src = (isQ ? Qi : Ki) + (long)row * D_DIM + hh * HD_DIM;
    __hip_bfloat16* dst = (isQ ? Qo : Ko) + (long)row * D_DIM + hh * HD_DIM;

    short8 xv = *(const short8*)&src[2 * p0];
    float4 cv = *(const float4*)&tab[pos * 32 + p0];
    float4 sv = *(const float4*)&tab[32768 + pos * 32 + p0];
    float cc[4] = {cv.x, cv.y, cv.z, cv.w};
    float ss[4] = {sv.x, sv.y, sv.z, sv.w};

    __hip_bfloat16 o1[4], o2[4];
#pragma unroll
    for (int j = 0; j < 4; ++j) {
        float x1 = bf2f(xv[2 * j]);
        float x2 = bf2f(xv[2 * j + 1]);
        o1[j] = __float2bfloat16((x1 * cc[j] - x2 * ss[j]) * scale);
        o2[j] = __float2bfloat16((x1 * ss[j] + x2 * cc[j]) * scale);
    }
    *(uint2*)&dst[p0]      = *(uint2*)o1;
    *(uint2*)&dst[p0 + 32] = *(uint2*)o2;
}

// ---------------------------------------------------------------------------
// MFMA flash attention, swapped-QK^T softmax, prefetched staging, balanced qt.
// ---------------------------------------------------------------------------
#define KPAD 72

__global__ __launch_bounds__(256, 2) void attn_mfma_kernel(
    const __hip_bfloat16* __restrict__ Q,
    const __hip_bfloat16* __restrict__ K,
    const __hip_bfloat16* __restrict__ Vt,
    __hip_bfloat16* __restrict__ CTX)
{
    __shared__ __align__(16) __hip_bfloat16 Kl[64][KPAD];
    __shared__ __align__(16) __hip_bfloat16 Vl[64][KPAD];
    __shared__ __align__(16) __hip_bfloat16 Pl[4][32][KPAD];
    __shared__ __align__(16) float aS[4][2][16];

    const int tid = threadIdx.x;
    const int l = tid & 63;
    const int w = tid >> 6;

    const int bid = blockIdx.x + 8 * blockIdx.y + 128 * blockIdx.z;
    const int half = bid >> 8;
    const int idx = bid & 255;
    int qt = idx & 7;
    if (half) qt = 7 - qt;
    const int rest = idx >> 3;
    const int h = rest & 15;
    const int b = (rest >> 4) | (half << 1);

    const int lrow = l & 15;
    const int kg = l >> 4;
    const int kg4 = kg * 4;

    const int q0w = qt * 128 + w * 32;
    const long qrow_base = (long)b * S_DIM + q0w;

    short8 qf[2][2];
#pragma unroll
    for (int m = 0; m < 2; ++m)
#pragma unroll
        for (int ks = 0; ks < 2; ++ks)
            qf[m][ks] = *(const short8*)&Q[(qrow_base + m * 16 + lrow) * D_DIM +
                                           h * HD_DIM + ks * 32 + kg * 8];

    f32x4 ctx[2][4];
#pragma unroll
    for (int m = 0; m < 2; ++m)
#pragma unroll
        for (int d = 0; d < 4; ++d) ctx[m][d] = (f32x4){0.f, 0.f, 0.f, 0.f};
    float mrun[2] = {-1e30f, -1e30f};
    float lrun[2] = {0.f, 0.f};

    const int sr = tid >> 2;
    const int sc2 = (tid & 3) * 16;
    const __hip_bfloat16* Kg = K + ((long)b * S_DIM + sr) * D_DIM + h * HD_DIM + sc2;
    const __hip_bfloat16* Vg = Vt + ((long)((b * H_DIM + h) * HD_DIM) + sr) * S_DIM + sc2;

    const int ktmax = 2 * qt + 1;

    short8 kp0 = *(const short8*)Kg;
    short8 kp1 = *(const short8*)(Kg + 8);
    short8 vp0 = *(const short8*)Vg;
    short8 vp1 = *(const short8*)(Vg + 8);

    for (int kt = 0; kt <= ktmax; ++kt) {
        __syncthreads();
        *(short8*)&Kl[sr][sc2]     = kp0;
        *(short8*)&Kl[sr][sc2 + 8] = kp1;
        *(short8*)&Vl[sr][sc2]     = vp0;
        *(short8*)&Vl[sr][sc2 + 8] = vp1;
        if (kt < ktmax) {
            const __hip_bfloat16* kp = Kg + (long)(kt + 1) * 64 * D_DIM;
            const __hip_bfloat16* vp = Vg + (kt + 1) * 64;
            kp0 = *(const short8*)kp;
            kp1 = *(const short8*)(kp + 8);
            vp0 = *(const short8*)vp;
            vp1 = *(const short8*)(vp + 8);
        }
        __syncthreads();

        if (kt * 64 > q0w + 31) continue;

        f32x4 sac[2][4];
#pragma unroll
        for (int m = 0; m < 2; ++m)
#pragma unroll
            for (int nt = 0; nt < 4; ++nt) sac[m][nt] = (f32x4){0.f, 0.f, 0.f, 0.f};

        short8 kf[4][2];
#pragma unroll
        for (int nt = 0; nt < 4; ++nt)
#pragma unroll
            for (int ks = 0; ks < 2; ++ks)
                kf[nt][ks] = *(const short8*)&Kl[nt * 16 + lrow][ks * 32 + kg * 8];
#pragma unroll
        for (int m = 0; m < 2; ++m)
#pragma unroll
            for (int nt = 0; nt < 4; ++nt)
#pragma unroll
                for (int ks = 0; ks < 2; ++ks)
                    sac[m][nt] = __builtin_amdgcn_mfma_f32_16x16x32_bf16(
                        kf[nt][ks], qf[m][ks], sac[m][nt], 0, 0, 0);

        const bool partial = (kt * 64 + 63 > q0w);
        const int kbase = kt * 64;
#pragma unroll
        for (int m = 0; m < 2; ++m) {
            const int qg = q0w + m * 16 + lrow;
            float s[16];
#pragma unroll
            for (int nt = 0; nt < 4; ++nt)
#pragma unroll
                for (int r = 0; r < 4; ++r) {
                    float v = sac[m][nt][r];
                    if (partial && (kbase + nt * 16 + kg4 + r > qg)) v = -1e30f;
                    s[nt * 4 + r] = v;
                }
            float t8[8];
#pragma unroll
            for (int i = 0; i < 8; ++i) t8[i] = fmaxf(s[i], s[i + 8]);
#pragma unroll
            for (int i = 0; i < 4; ++i) t8[i] = fmaxf(t8[i], t8[i + 4]);
            float mx = fmaxf(fmaxf(t8[0], t8[1]), fmaxf(t8[2], t8[3]));
            mx = fmaxf(mx, __shfl_xor(mx, 16));
            mx = fmaxf(mx, __shfl_xor(mx, 32));
            const float mnew = fmaxf(mrun[m], mx);
            const float alpha = __expf(mrun[m] - mnew);
            mrun[m] = mnew;

            float p0s = 0.f, p1s = 0.f, p2s = 0.f, p3s = 0.f;
            __attribute__((aligned(8))) __hip_bfloat16 pb[16];
#pragma unroll
            for (int i = 0; i < 4; ++i) {
                float p = __expf(s[i] - mnew);      p0s += p; pb[i] = __float2bfloat16(p);
            }
#pragma unroll
            for (int i = 4; i < 8; ++i) {
                float p = __expf(s[i] - mnew);      p1s += p; pb[i] = __float2bfloat16(p);
            }
#pragma unroll
            for (int i = 8; i < 12; ++i) {
                float p = __expf(s[i] - mnew);      p2s += p; pb[i] = __float2bfloat16(p);
            }
#pragma unroll
            for (int i = 12; i < 16; ++i) {
                float p = __expf(s[i] - mnew);      p3s += p; pb[i] = __float2bfloat16(p);
            }
            float sum = (p0s + p1s) + (p2s + p3s);
            sum += __shfl_xor(sum, 16);
            sum += __shfl_xor(sum, 32);
            lrun[m] = lrun[m] * alpha + sum;

            if (kg == 0) aS[w][m][lrow] = alpha;
#pragma unroll
            for (int nt = 0; nt < 4; ++nt)
                *(uint2*)&Pl[w][m * 16 + lrow][nt * 16 + kg4] = *(uint2*)&pb[nt * 4];
        }

#pragma unroll
        for (int m = 0; m < 2; ++m) {
            f32x4 al4 = *(const f32x4*)&aS[w][m][kg4];
#pragma unroll
            for (int dt = 0; dt < 4; ++dt)
#pragma unroll
                for (int r = 0; r < 4; ++r) ctx[m][dt][r] *= al4[r];
        }

        short8 vf[4][2];
#pragma unroll
        for (int dt = 0; dt < 4; ++dt)
#pragma unroll
            for (int ks = 0; ks < 2; ++ks)
                vf[dt][ks] = *(const short8*)&Vl[dt * 16 + lrow][ks * 32 + kg * 8];
#pragma unroll
        for (int m = 0; m < 2; ++m) {
            short8 pf[2];
#pragma unroll
            for (int ks = 0; ks < 2; ++ks)
                pf[ks] = *(const short8*)&Pl[w][m * 16 + lrow][ks * 32 + kg * 8];
#pragma unroll
            for (int dt = 0; dt < 4; ++dt)
#pragma unroll
                for (int ks = 0; ks < 2; ++ks)
                    ctx[m][dt] = __builtin_amdgcn_mfma_f32_16x16x32_bf16(
                        pf[ks], vf[dt][ks], ctx[m][dt], 0, 0, 0);
        }
    }

    if (kg == 0) {
        aS[w][0][lrow] = lrun[0];
        aS[w][1][lrow] = lrun[1];
    }
#pragma unroll
    for (int m = 0; m < 2; ++m) {
        f32x4 lv = *(const f32x4*)&aS[w][m][kg4];
#pragma unroll
        for (int r = 0; r < 4; ++r) {
            const float inv_l = 1.0f / lv[r];
            const long rowoff = (qrow_base + m * 16 + kg4 + r) * D_DIM + h * HD_DIM;
#pragma unroll
            for (int dt = 0; dt < 4; ++dt)
                CTX[rowoff + dt * 16 + lrow] = __float2bfloat16(ctx[m][dt][r] * inv_l);
        }
    }
}

// ---------------------------------------------------------------------------
extern "C" void kernel_launch(void* const* d_in, const int* in_sizes, int n_in,
                              void* d_out, int out_size, void* d_ws, size_t ws_size,
                              hipStream_t stream)
{
    const float* query = (const float*)d_in[0];
    const float* key   = (const float*)d_in[1];
    const float* value = (const float*)d_in[2];
    const float* Wq = (const float*)d_in[4];
    const float* bq = (const float*)d_in[5];
    const float* Wk = (const float*)d_in[6];
    const float* bk = (const float*)d_in[7];
    const float* Wv = (const float*)d_in[8];
    const float* bv = (const float*)d_in[9];
    const float* Wo = (const float*)d_in[10];
    const float* bo = (const float*)d_in[11];

    char* wsb = (char*)d_ws;
    __hip_bfloat16* Qw    = (__hip_bfloat16*)(wsb);                 // 8 MB (pre-rope)
    __hip_bfloat16* Kw    = (__hip_bfloat16*)(wsb + (8L  << 20));   // 8 MB
    __hip_bfloat16* Vtb   = (__hip_bfloat16*)(wsb + (16L << 20));   // 8 MB
    __hip_bfloat16* Qr    = (__hip_bfloat16*)(wsb + (24L << 20));   // 8 MB (roped)
    __hip_bfloat16* Kr    = (__hip_bfloat16*)(wsb + (32L << 20));   // 8 MB (roped)
    __hip_bfloat16* CTXbf = (__hip_bfloat16*)(wsb + (40L << 20));   // 8 MB
    __hip_bfloat16* WtQ   = (__hip_bfloat16*)(wsb + (48L << 20));   // 2 MB
    __hip_bfloat16* WtK   = (__hip_bfloat16*)(wsb + (50L << 20));
    __hip_bfloat16* WtV   = (__hip_bfloat16*)(wsb + (52L << 20));
    __hip_bfloat16* WtO   = (__hip_bfloat16*)(wsb + (54L << 20));
    float*          tab   = (float*)(wsb + (56L << 20));            // 256 KB

    preamble_kernel<<<dim3(32, 32, 5), 256, 0, stream>>>(
        Wq, Wk, Wv, Wo, WtQ, WtK, WtV, WtO, tab);

    gemm_qkv_kernel<<<dim3(8, 32, 3), 256, 0, stream>>>(
        query, key, value, WtQ, WtK, WtV, bq, bk, bv, Qw, Kw, Vtb);

    rope_bf16_kernel<<<dim3(2048, 2), 256, 0, stream>>>(Qw, Kw, Qr, Kr, tab);

    attn_mfma_kernel<<<dim3(8, 16, 4), 256, 0, stream>>>(Qr, Kr, Vtb, CTXbf);

    gemm_wo_kernel<<<512, 256, 0, stream>>>(CTXbf, WtO, bo, (float*)d_out);
}